// Round 1
// baseline (1014.181 us; speedup 1.0000x reference)
//
#include <hip/hip_runtime.h>
#include <hip/hip_bf16.h>

// Problem constants
#define BATCH 8192
#define NNODE 20
#define DMODEL 256
#define NHEAD 8
#define MROWS (BATCH * NNODE)   // 163840
#define KCONV 768               // conv GEMM K (3 taps x 256 ch)
#define NCONV 768               // conv GEMM N (q|k|v)

typedef __bf16 bf16x8 __attribute__((ext_vector_type(8)));
typedef float f32x4 __attribute__((ext_vector_type(4)));

// ---------------------------------------------------------------------------
// K1: prep — cast x to bf16, build WcT[n][j] bf16 (n=c*256+o, j=t*256+i,
// val = w_c[o,i,t]), cast wo to bf16.
// ---------------------------------------------------------------------------
__global__ void prep_kernel(const float* __restrict__ x,
                            const float* __restrict__ wq,
                            const float* __restrict__ wk,
                            const float* __restrict__ wv,
                            const float* __restrict__ wo,
                            __hip_bfloat16* __restrict__ xb,
                            __hip_bfloat16* __restrict__ WcT,
                            __hip_bfloat16* __restrict__ wob) {
  const int stride = gridDim.x * blockDim.x;
  const int gid = blockIdx.x * blockDim.x + threadIdx.x;

  // x -> bf16, 8 elements per thread
  const int n8 = (MROWS * DMODEL) / 8;
  for (int i8 = gid; i8 < n8; i8 += stride) {
    const float4* xp = ((const float4*)x) + (size_t)i8 * 2;
    float4 a = xp[0];
    float4 b = xp[1];
    __align__(16) __hip_bfloat16 h[8];
    h[0] = __float2bfloat16(a.x); h[1] = __float2bfloat16(a.y);
    h[2] = __float2bfloat16(a.z); h[3] = __float2bfloat16(a.w);
    h[4] = __float2bfloat16(b.x); h[5] = __float2bfloat16(b.y);
    h[6] = __float2bfloat16(b.z); h[7] = __float2bfloat16(b.w);
    ((int4*)xb)[i8] = *(const int4*)h;
  }

  // WcT: [768 n][768 j], j = t*256 + i (tap-major so 64-chunks stay in one tap)
  for (int idx = gid; idx < NCONV * KCONV; idx += stride) {
    int n = idx / KCONV;
    int j = idx - n * KCONV;
    int c = n >> 8, o = n & 255;
    int t = j >> 8, i = j & 255;
    const float* w = (c == 0) ? wq : (c == 1) ? wk : wv;
    WcT[idx] = __float2bfloat16(w[(o * 256 + i) * 3 + t]);
  }

  // wo -> bf16 (layout [O][D] is already B[n=o][k=d])
  for (int idx = gid; idx < DMODEL * DMODEL; idx += stride) {
    wob[idx] = __float2bfloat16(wo[idx]);
  }
}

// ---------------------------------------------------------------------------
// K2: conv GEMM. C[M=163840][768] = unfold(xb)[M][768] @ WcT^T.
// 128x128 tile, 256 threads (4 waves as 2x2 of 64x64), 16x16x32 bf16 MFMA.
// LDS K-stride padded 64->72 (+16B: keeps b128 alignment, 2-way bank alias=free)
// ---------------------------------------------------------------------------
__global__ void conv_gemm_kernel(const __hip_bfloat16* __restrict__ xb,
                                 const __hip_bfloat16* __restrict__ WcT,
                                 __hip_bfloat16* __restrict__ y) {
  __shared__ __align__(16) __hip_bfloat16 As[128][72];
  __shared__ __align__(16) __hip_bfloat16 Bs[128][72];

  const int tid = threadIdx.x;
  const int lane = tid & 63;
  const int wave = tid >> 6;
  const int wm = (wave >> 1) << 6;   // 0 / 64
  const int wn = (wave & 1) << 6;    // 0 / 64
  const int l16 = lane & 15;
  const int quad = lane >> 4;
  const int m0 = blockIdx.x * 128;
  const int n0 = blockIdx.y * 128;

  f32x4 acc[4][4];
  const f32x4 zero = {0.f, 0.f, 0.f, 0.f};
#pragma unroll
  for (int i = 0; i < 4; ++i)
#pragma unroll
    for (int j = 0; j < 4; ++j) acc[i][j] = zero;

  for (int kt = 0; kt < 12; ++kt) {
    const int k0 = kt * 64;
    const int t = k0 >> 8;       // conv tap for this whole K-chunk
    const int i0 = k0 & 255;     // channel base

    // stage A (unfolded x) and B (WcT) tiles: 128 rows x 64 bf16, 16B/thread x4
#pragma unroll
    for (int it = 0; it < 4; ++it) {
      int idx = tid + it * 256;
      int row = idx >> 3;
      int seg = idx & 7;
      // A
      int gr = m0 + row;
      int b = gr / 20;
      int node = gr - b * 20;
      int xr = node + t - 1;
      int4 val = {0, 0, 0, 0};
      if ((unsigned)xr < 20u) {
        val = *(const int4*)(xb + (((size_t)(b * 20 + xr)) << 8) + i0 + (seg << 3));
      }
      *(int4*)&As[row][seg << 3] = val;
      // B
      int gn = n0 + row;
      *(int4*)&Bs[row][seg << 3] =
          *(const int4*)(WcT + (size_t)gn * KCONV + k0 + (seg << 3));
    }
    __syncthreads();

#pragma unroll
    for (int kk = 0; kk < 64; kk += 32) {
      bf16x8 af[4], bfr[4];
#pragma unroll
      for (int i = 0; i < 4; ++i)
        af[i] = *(const bf16x8*)&As[wm + i * 16 + l16][kk + quad * 8];
#pragma unroll
      for (int j = 0; j < 4; ++j)
        bfr[j] = *(const bf16x8*)&Bs[wn + j * 16 + l16][kk + quad * 8];
#pragma unroll
      for (int i = 0; i < 4; ++i)
#pragma unroll
        for (int j = 0; j < 4; ++j)
          acc[i][j] = __builtin_amdgcn_mfma_f32_16x16x32_bf16(af[i], bfr[j],
                                                              acc[i][j], 0, 0, 0);
    }
    __syncthreads();
  }

  // epilogue: D[row=(lane>>4)*4+r][col=lane&15] per 16x16 tile (m89-verified)
#pragma unroll
  for (int i = 0; i < 4; ++i)
#pragma unroll
    for (int j = 0; j < 4; ++j)
#pragma unroll
      for (int r = 0; r < 4; ++r) {
        int row = m0 + wm + i * 16 + quad * 4 + r;
        int col = n0 + wn + j * 16 + l16;
        y[(size_t)row * NCONV + col] = __float2bfloat16(acc[i][j][r]);
      }
}

// ---------------------------------------------------------------------------
// K3: per-batch attention. LN(conv)+residual -> q,k,v in LDS (stride 257:
// conflict-free), scores + rel bias + gbias, softmax, A@V -> bf16.
// ---------------------------------------------------------------------------
__global__ void attn_kernel(const float* __restrict__ x,
                            const __hip_bfloat16* __restrict__ y,
                            const float* __restrict__ gq, const float* __restrict__ bq,
                            const float* __restrict__ gk, const float* __restrict__ bk,
                            const float* __restrict__ gv, const float* __restrict__ bv,
                            const float* __restrict__ rel,
                            const float* __restrict__ gbias,
                            const float* __restrict__ alpha_p,
                            __hip_bfloat16* __restrict__ ao) {
  __shared__ float qS[20 * 257];
  __shared__ float kS[20 * 257];
  __shared__ float vS[20 * 257];
  __shared__ float scS[8 * 20 * 20];

  const int b = blockIdx.x;
  const int tid = threadIdx.x;
  const int lane = tid & 63;
  const int wave = tid >> 6;
  const float alpha = alpha_p[0];

  // LN + residual: 60 rows (20 nodes x {q,k,v}), one wave per row
#pragma unroll 1
  for (int m = 0; m < 15; ++m) {
    int r = wave + (m << 2);          // 0..59
    int node = r / 3;
    int c = r - node * 3;
    const float* g = (c == 0) ? gq : (c == 1) ? gk : gv;
    const float* bb = (c == 0) ? bq : (c == 1) ? bk : bv;
    float* dst = (c == 0) ? qS : (c == 1) ? kS : vS;
    const __hip_bfloat16* yrow = y + ((size_t)(b * 20 + node)) * NCONV + c * 256;
    const float* xrow = x + (((size_t)(b * 20 + node)) << 8);

    float vals[4];
    float sum = 0.f, sq = 0.f;
#pragma unroll
    for (int s = 0; s < 4; ++s) {
      float f = __bfloat162float(yrow[lane + (s << 6)]);
      vals[s] = f;
      sum += f;
      sq += f * f;
    }
#pragma unroll
    for (int off = 32; off > 0; off >>= 1) {
      sum += __shfl_xor(sum, off, 64);
      sq += __shfl_xor(sq, off, 64);
    }
    float mean = sum * (1.0f / 256.0f);
    float var = sq * (1.0f / 256.0f) - mean * mean;
    float rstd = rsqrtf(var + 1e-5f);
#pragma unroll
    for (int s = 0; s < 4; ++s) {
      int d = lane + (s << 6);
      dst[node * 257 + d] = xrow[d] + (vals[s] - mean) * rstd * g[d] + bb[d];
    }
  }
  __syncthreads();

  // scores: 8 heads x 20 x 20
  for (int flat = tid; flat < 3200; flat += 256) {
    int h = flat / 400;
    int rem = flat - h * 400;
    int i = rem / 20;
    int j = rem - i * 20;
    const float* qr = qS + i * 257 + h * 32;
    const float* kr = kS + j * 257 + h * 32;
    float dot = 0.f;
#pragma unroll
    for (int d = 0; d < 32; ++d) dot += qr[d] * kr[d];
    scS[flat] = dot * 0.17677669529663687f + rel[(i - j + 19) * 8 + h] +
                gbias[flat] * alpha;
  }
  __syncthreads();

  // softmax over last dim: 160 rows
  if (tid < 160) {
    float* row = scS + tid * 20;
    float mx = row[0];
#pragma unroll
    for (int j = 1; j < 20; ++j) mx = fmaxf(mx, row[j]);
    float s = 0.f;
    float e[20];
#pragma unroll
    for (int j = 0; j < 20; ++j) {
      e[j] = __expf(row[j] - mx);
      s += e[j];
    }
    float inv = 1.0f / s;
#pragma unroll
    for (int j = 0; j < 20; ++j) row[j] = e[j] * inv;
  }
  __syncthreads();

  // A@V: out[i][col] = sum_j attn[h(col)][i][j] * v[j][col]
  for (int flat = tid; flat < 5120; flat += 256) {
    int i = flat >> 8;
    int col = flat & 255;
    int h = col >> 5;
    const float* ar = scS + h * 400 + i * 20;
    float a = 0.f;
#pragma unroll
    for (int j = 0; j < 20; ++j) a += ar[j] * vS[j * 257 + col];
    ao[(((size_t)(b * 20 + i)) << 8) + col] = __float2bfloat16(a);
  }
}

// ---------------------------------------------------------------------------
// K4: output projection GEMM. out[M][256] = ao[M][256] @ wob^T + bo (fp32 out)
// Same tile structure as K2, K=256.
// ---------------------------------------------------------------------------
__global__ void proj_gemm_kernel(const __hip_bfloat16* __restrict__ ao,
                                 const __hip_bfloat16* __restrict__ wob,
                                 const float* __restrict__ bo,
                                 float* __restrict__ out) {
  __shared__ __align__(16) __hip_bfloat16 As[128][72];
  __shared__ __align__(16) __hip_bfloat16 Bs[128][72];

  const int tid = threadIdx.x;
  const int lane = tid & 63;
  const int wave = tid >> 6;
  const int wm = (wave >> 1) << 6;
  const int wn = (wave & 1) << 6;
  const int l16 = lane & 15;
  const int quad = lane >> 4;
  const int m0 = blockIdx.x * 128;
  const int n0 = blockIdx.y * 128;

  f32x4 acc[4][4];
  const f32x4 zero = {0.f, 0.f, 0.f, 0.f};
#pragma unroll
  for (int i = 0; i < 4; ++i)
#pragma unroll
    for (int j = 0; j < 4; ++j) acc[i][j] = zero;

  for (int kt = 0; kt < 4; ++kt) {
    const int k0 = kt * 64;
#pragma unroll
    for (int it = 0; it < 4; ++it) {
      int idx = tid + it * 256;
      int row = idx >> 3;
      int seg = idx & 7;
      int gr = m0 + row;
      *(int4*)&As[row][seg << 3] =
          *(const int4*)(ao + ((size_t)gr << 8) + k0 + (seg << 3));
      int gn = n0 + row;
      *(int4*)&Bs[row][seg << 3] =
          *(const int4*)(wob + ((size_t)gn << 8) + k0 + (seg << 3));
    }
    __syncthreads();

#pragma unroll
    for (int kk = 0; kk < 64; kk += 32) {
      bf16x8 af[4], bfr[4];
#pragma unroll
      for (int i = 0; i < 4; ++i)
        af[i] = *(const bf16x8*)&As[wm + i * 16 + l16][kk + quad * 8];
#pragma unroll
      for (int j = 0; j < 4; ++j)
        bfr[j] = *(const bf16x8*)&Bs[wn + j * 16 + l16][kk + quad * 8];
#pragma unroll
      for (int i = 0; i < 4; ++i)
#pragma unroll
        for (int j = 0; j < 4; ++j)
          acc[i][j] = __builtin_amdgcn_mfma_f32_16x16x32_bf16(af[i], bfr[j],
                                                              acc[i][j], 0, 0, 0);
    }
    __syncthreads();
  }

#pragma unroll
  for (int i = 0; i < 4; ++i)
#pragma unroll
    for (int j = 0; j < 4; ++j) {
      int col = n0 + wn + j * 16 + l16;
      float bias = bo[col];
#pragma unroll
      for (int r = 0; r < 4; ++r) {
        int row = m0 + wm + i * 16 + quad * 4 + r;
        out[(size_t)row * DMODEL + col] = acc[i][j][r] + bias;
      }
    }
}

// ---------------------------------------------------------------------------
// launch
// ---------------------------------------------------------------------------
extern "C" void kernel_launch(void* const* d_in, const int* in_sizes, int n_in,
                              void* d_out, int out_size, void* d_ws, size_t ws_size,
                              hipStream_t stream) {
  const float* x     = (const float*)d_in[0];
  const float* wq    = (const float*)d_in[1];
  const float* wk    = (const float*)d_in[2];
  const float* wv    = (const float*)d_in[3];
  const float* gq    = (const float*)d_in[4];
  const float* bq    = (const float*)d_in[5];
  const float* gk    = (const float*)d_in[6];
  const float* bk    = (const float*)d_in[7];
  const float* gv    = (const float*)d_in[8];
  const float* bv    = (const float*)d_in[9];
  const float* rel   = (const float*)d_in[10];
  const float* gbias = (const float*)d_in[11];
  const float* alpha = (const float*)d_in[12];
  const float* wo    = (const float*)d_in[13];
  const float* bo    = (const float*)d_in[14];
  float* out = (float*)d_out;

  // workspace layout (bytes), all 16B aligned; total 420,741,120
  char* ws = (char*)d_ws;
  __hip_bfloat16* xb  = (__hip_bfloat16*)(ws);                 // 83,886,080
  __hip_bfloat16* y   = (__hip_bfloat16*)(ws + 83886080);      // 251,658,240
  __hip_bfloat16* ao  = (__hip_bfloat16*)(ws + 335544320);     // 83,886,080
  __hip_bfloat16* WcT = (__hip_bfloat16*)(ws + 419430400);     // 1,179,648
  __hip_bfloat16* wob = (__hip_bfloat16*)(ws + 420610048);     // 131,072

  prep_kernel<<<8192, 256, 0, stream>>>(x, wq, wk, wv, wo, xb, WcT, wob);
  conv_gemm_kernel<<<dim3(1280, 6), 256, 0, stream>>>(xb, WcT, y);
  attn_kernel<<<8192, 256, 0, stream>>>(x, y, gq, bq, gk, bk, gv, bv, rel,
                                        gbias, alpha, ao);
  proj_gemm_kernel<<<dim3(1280, 2), 256, 0, stream>>>(ao, wob, bo, out);
}

// Round 2
// 864.979 us; speedup vs baseline: 1.1725x; 1.1725x over previous
//
#include <hip/hip_runtime.h>
#include <hip/hip_bf16.h>
#include <stdint.h>

#define BATCH 8192
#define NNODE 20
#define MROWS 163840
#define KCONV 768
#define NCONV 768

typedef __bf16 bf16x8 __attribute__((ext_vector_type(8)));
typedef float f32x4 __attribute__((ext_vector_type(4)));
typedef unsigned short u16x4 __attribute__((ext_vector_type(4)));

#define GLOBAL_AS __attribute__((address_space(1)))
#define LDS_AS __attribute__((address_space(3)))

__device__ __forceinline__ void load_lds16(const void* g, void* l) {
  __builtin_amdgcn_global_load_lds((const GLOBAL_AS uint32_t*)g,
                                   (LDS_AS uint32_t*)l, 16, 0, 0);
}

__device__ __forceinline__ float bf2f(unsigned short u) {
  union { unsigned int i; float f; } x;
  x.i = ((unsigned int)u) << 16;
  return x.f;
}

// ---------------------------------------------------------------------------
// K1: prep — cast x to bf16, build WcT (B-matrix for conv GEMM), cast wo,
// zero the boundary row used by conv staging.
// ---------------------------------------------------------------------------
__global__ void prep_kernel(const float* __restrict__ x,
                            const float* __restrict__ wq,
                            const float* __restrict__ wk,
                            const float* __restrict__ wv,
                            const float* __restrict__ wo,
                            __hip_bfloat16* __restrict__ xb,
                            __hip_bfloat16* __restrict__ WcT,
                            __hip_bfloat16* __restrict__ wob,
                            int* __restrict__ zrow) {
  const int stride = gridDim.x * blockDim.x;
  const int gid = blockIdx.x * blockDim.x + threadIdx.x;

  if (gid < 128) zrow[gid] = 0;  // 512B zero block for conv boundary lanes

  const int n8 = (MROWS * 256) / 8;
  for (int i8 = gid; i8 < n8; i8 += stride) {
    const float4* xp = ((const float4*)x) + (size_t)i8 * 2;
    float4 a = xp[0];
    float4 b = xp[1];
    __align__(16) __hip_bfloat16 h[8];
    h[0] = __float2bfloat16(a.x); h[1] = __float2bfloat16(a.y);
    h[2] = __float2bfloat16(a.z); h[3] = __float2bfloat16(a.w);
    h[4] = __float2bfloat16(b.x); h[5] = __float2bfloat16(b.y);
    h[6] = __float2bfloat16(b.z); h[7] = __float2bfloat16(b.w);
    ((int4*)xb)[i8] = *(const int4*)h;
  }

  // WcT[n][j]: n = c*256+o, j = t*256+i, val = w_c[o,i,t]
  for (int idx = gid; idx < NCONV * KCONV; idx += stride) {
    int n = idx / KCONV;
    int j = idx - n * KCONV;
    int c = n >> 8, o = n & 255;
    int t = j >> 8, i = j & 255;
    const float* w = (c == 0) ? wq : (c == 1) ? wk : wv;
    WcT[idx] = __float2bfloat16(w[(o * 256 + i) * 3 + t]);
  }

  for (int idx = gid; idx < 256 * 256; idx += stride) {
    wob[idx] = __float2bfloat16(wo[idx]);
  }
}

// ---------------------------------------------------------------------------
// K2: conv GEMM, m97 recipe: global_load_lds width-16, unpadded [128][64]
// LDS with XOR swizzle applied on the GLOBAL source chunk index (LDS dest
// must stay lane-contiguous). Boundary taps -> redirect lanes to zrow.
// ---------------------------------------------------------------------------
__global__ __launch_bounds__(256) void conv_gemm_kernel(
    const __hip_bfloat16* __restrict__ xb,
    const __hip_bfloat16* __restrict__ WcT,
    __hip_bfloat16* __restrict__ y,
    const __hip_bfloat16* __restrict__ zrow) {
  __shared__ __align__(16) __hip_bfloat16 As[128 * 64];
  __shared__ __align__(16) __hip_bfloat16 Bs[128 * 64];

  const int tid = threadIdx.x;
  const int lane = tid & 63;
  const int wave = tid >> 6;
  const int wm = (wave >> 1) << 6;
  const int wn = (wave & 1) << 6;
  const int l16 = lane & 15;
  const int quad = lane >> 4;
  const int m0 = blockIdx.x * 128;
  const int n0 = blockIdx.y * 128;

  // staging geometry: flat = (it*4+wave)*64 + lane; row=flat>>3; seg=flat&7
  const __hip_bfloat16* a_base[4];
  const __hip_bfloat16* z_base[4];
  const __hip_bfloat16* b_base[4];
  int a_node[4];
  int lds_off[4];
#pragma unroll
  for (int it = 0; it < 4; ++it) {
    int flat = ((it * 4 + wave) << 6) + lane;
    int row = flat >> 3;
    int seg = flat & 7;
    int seg_g = seg ^ (row & 7);  // XOR swizzle on global source
    int gr = m0 + row;
    int b = gr / 20;
    int node = gr - b * 20;
    a_node[it] = node;
    a_base[it] = xb + (long)(gr - 1) * 256 + seg_g * 8;
    z_base[it] = zrow + seg_g * 8;
    b_base[it] = WcT + (size_t)(n0 + row) * KCONV + seg_g * 8;
    lds_off[it] = (it * 4 + wave) << 9;  // 512 elems per instruction
  }

  f32x4 acc[4][4];
  const f32x4 zero = {0.f, 0.f, 0.f, 0.f};
#pragma unroll
  for (int i = 0; i < 4; ++i)
#pragma unroll
    for (int j = 0; j < 4; ++j) acc[i][j] = zero;

  for (int kt = 0; kt < 12; ++kt) {
    const int t = kt >> 2;
    const int i0 = (kt & 3) << 6;
    const int k0 = kt << 6;
#pragma unroll
    for (int it = 0; it < 4; ++it) {
      bool ok = (unsigned)(a_node[it] + t - 1) < 20u;
      const __hip_bfloat16* ga = ok ? (a_base[it] + t * 256 + i0) : z_base[it];
      load_lds16(ga, &As[lds_off[it]]);
      load_lds16(b_base[it] + k0, &Bs[lds_off[it]]);
    }
    __syncthreads();

#pragma unroll
    for (int kk = 0; kk < 64; kk += 32) {
      const int sx = (((kk >> 3) + quad) ^ (l16 & 7)) << 3;
      bf16x8 af[4], bfr[4];
#pragma unroll
      for (int i = 0; i < 4; ++i)
        af[i] = *(const bf16x8*)&As[((wm + i * 16 + l16) << 6) + sx];
#pragma unroll
      for (int j = 0; j < 4; ++j)
        bfr[j] = *(const bf16x8*)&Bs[((wn + j * 16 + l16) << 6) + sx];
#pragma unroll
      for (int i = 0; i < 4; ++i)
#pragma unroll
        for (int j = 0; j < 4; ++j)
          acc[i][j] = __builtin_amdgcn_mfma_f32_16x16x32_bf16(af[i], bfr[j],
                                                              acc[i][j], 0, 0, 0);
    }
    __syncthreads();
  }

#pragma unroll
  for (int i = 0; i < 4; ++i)
#pragma unroll
    for (int j = 0; j < 4; ++j)
#pragma unroll
      for (int r = 0; r < 4; ++r) {
        int row = m0 + wm + i * 16 + quad * 4 + r;
        int col = n0 + wn + j * 16 + l16;
        y[(size_t)row * NCONV + col] = __float2bfloat16(acc[i][j][r]);
      }
}

// ---------------------------------------------------------------------------
// K3a: LayerNorm + residual, in place on y. One wave per (b,node) row,
// all 3 of q/k/v handled by the same wave (shares residual load, ILP).
// ---------------------------------------------------------------------------
__global__ void ln_kernel(__hip_bfloat16* __restrict__ y,
                          const __hip_bfloat16* __restrict__ xb,
                          const float* __restrict__ gq, const float* __restrict__ bq,
                          const float* __restrict__ gk, const float* __restrict__ bk,
                          const float* __restrict__ gv, const float* __restrict__ bv) {
  const int lane = threadIdx.x & 63;
  const int wave = threadIdx.x >> 6;
  const int row = blockIdx.x * 4 + wave;
  const int d0 = lane << 2;

  u16x4 yv[3];
#pragma unroll
  for (int c = 0; c < 3; ++c)
    yv[c] = *(const u16x4*)&y[(size_t)row * 768 + c * 256 + d0];
  u16x4 xv = *(const u16x4*)&xb[((size_t)row << 8) + d0];

  float4 g4[3], b4[3];
  g4[0] = *(const float4*)&gq[d0]; b4[0] = *(const float4*)&bq[d0];
  g4[1] = *(const float4*)&gk[d0]; b4[1] = *(const float4*)&bk[d0];
  g4[2] = *(const float4*)&gv[d0]; b4[2] = *(const float4*)&bv[d0];

  float f[3][4];
  float sum[3] = {0.f, 0.f, 0.f}, sq[3] = {0.f, 0.f, 0.f};
#pragma unroll
  for (int c = 0; c < 3; ++c)
#pragma unroll
    for (int s = 0; s < 4; ++s) {
      float v = bf2f(yv[c][s]);
      f[c][s] = v;
      sum[c] += v;
      sq[c] += v * v;
    }
#pragma unroll
  for (int off = 32; off > 0; off >>= 1)
#pragma unroll
    for (int c = 0; c < 3; ++c) {
      sum[c] += __shfl_xor(sum[c], off, 64);
      sq[c] += __shfl_xor(sq[c], off, 64);
    }

  float rx[4];
#pragma unroll
  for (int s = 0; s < 4; ++s) rx[s] = bf2f(xv[s]);

#pragma unroll
  for (int c = 0; c < 3; ++c) {
    float mean = sum[c] * (1.0f / 256.0f);
    float var = sq[c] * (1.0f / 256.0f) - mean * mean;
    float rstd = rsqrtf(var + 1e-5f);
    const float* g = (const float*)&g4[c];
    const float* bb = (const float*)&b4[c];
    __align__(8) __hip_bfloat16 h[4];
#pragma unroll
    for (int s = 0; s < 4; ++s)
      h[s] = __float2bfloat16(rx[s] + (f[c][s] - mean) * rstd * g[s] + bb[s]);
    *(int2*)&y[(size_t)row * 768 + c * 256 + d0] = *(const int2*)h;
  }
}

// ---------------------------------------------------------------------------
// K3b: attention per batch. y (post-LN q|k|v) slab 20x768 bf16 -> LDS
// (stride padded 768->776 to break the 1536B bank alignment), register-
// tiled scores (1x4 j), softmax, register-tiled AV (4x1 i).
// ---------------------------------------------------------------------------
#define YST 776
__global__ __launch_bounds__(256) void attn2_kernel(
    const __hip_bfloat16* __restrict__ y,
    const float* __restrict__ rel,
    const float* __restrict__ gbias,
    const float* __restrict__ alpha_p,
    __hip_bfloat16* __restrict__ ao) {
  __shared__ __align__(16) __hip_bfloat16 yS[20 * YST];
  __shared__ float scS[8 * 20 * 20];

  const int b = blockIdx.x;
  const int tid = threadIdx.x;
  const float alpha = alpha_p[0];

  // stage 20x768 bf16 = 1920 int4 chunks
  const int4* src4 = (const int4*)(y + (size_t)b * NNODE * 768);
#pragma unroll
  for (int p = 0; p < 8; ++p) {
    int idx = tid + p * 256;
    if (idx < 1920) {
      int r = idx / 96;
      int c = idx - r * 96;
      *(int4*)&yS[r * YST + c * 8] = src4[idx];
    }
  }
  __syncthreads();

  // scores: 800 tasks of (h, i, j0..j0+3)
#pragma unroll
  for (int p = 0; p < 4; ++p) {
    int flat = tid + p * 256;
    if (flat < 800) {
      int h = flat / 100;
      int rem = flat - h * 100;
      int i = rem / 5;
      int j0 = (rem - i * 5) * 4;
      const unsigned short* qp = (const unsigned short*)&yS[i * YST + h * 32];
      float qf[32];
#pragma unroll
      for (int d = 0; d < 32; ++d) qf[d] = bf2f(qp[d]);
      float4 gb4 = *(const float4*)&gbias[h * 400 + i * 20 + j0];
#pragma unroll
      for (int jj = 0; jj < 4; ++jj) {
        int j = j0 + jj;
        const unsigned short* kp = (const unsigned short*)&yS[j * YST + 256 + h * 32];
        float dot = 0.f;
#pragma unroll
        for (int d = 0; d < 32; ++d) dot += qf[d] * bf2f(kp[d]);
        scS[h * 400 + i * 20 + j] = dot * 0.17677669529663687f +
                                    rel[(i - j + 19) * 8 + h] +
                                    ((const float*)&gb4)[jj] * alpha;
      }
    }
  }
  __syncthreads();

  // softmax: 160 rows
  if (tid < 160) {
    float* row = scS + tid * 20;
    float mx = row[0];
#pragma unroll
    for (int j = 1; j < 20; ++j) mx = fmaxf(mx, row[j]);
    float s = 0.f;
    float e[20];
#pragma unroll
    for (int j = 0; j < 20; ++j) {
      e[j] = __expf(row[j] - mx);
      s += e[j];
    }
    float inv = 1.0f / s;
#pragma unroll
    for (int j = 0; j < 20; ++j) row[j] = e[j] * inv;
  }
  __syncthreads();

  // AV: 1280 tasks of (col, i0..i0+3)
#pragma unroll
  for (int p = 0; p < 5; ++p) {
    int flat = tid + p * 256;
    int col = flat & 255;
    int i0 = (flat >> 8) << 2;
    int h = col >> 5;
    const unsigned short* vp = (const unsigned short*)yS;
    float o[4] = {0.f, 0.f, 0.f, 0.f};
#pragma unroll
    for (int j = 0; j < 20; ++j) {
      float vv = bf2f(vp[j * YST + 512 + col]);
#pragma unroll
      for (int ii = 0; ii < 4; ++ii)
        o[ii] += scS[h * 400 + (i0 + ii) * 20 + j] * vv;
    }
#pragma unroll
    for (int ii = 0; ii < 4; ++ii)
      ao[(((size_t)(b * NNODE + i0 + ii)) << 8) + col] = __float2bfloat16(o[ii]);
  }
}

// ---------------------------------------------------------------------------
// K4: output projection GEMM, same m97 recipe (no boundary logic).
// ---------------------------------------------------------------------------
__global__ __launch_bounds__(256) void proj_gemm_kernel(
    const __hip_bfloat16* __restrict__ ao,
    const __hip_bfloat16* __restrict__ wob,
    const float* __restrict__ bo,
    float* __restrict__ out) {
  __shared__ __align__(16) __hip_bfloat16 As[128 * 64];
  __shared__ __align__(16) __hip_bfloat16 Bs[128 * 64];

  const int tid = threadIdx.x;
  const int lane = tid & 63;
  const int wave = tid >> 6;
  const int wm = (wave >> 1) << 6;
  const int wn = (wave & 1) << 6;
  const int l16 = lane & 15;
  const int quad = lane >> 4;
  const int m0 = blockIdx.x * 128;
  const int n0 = blockIdx.y * 128;

  const __hip_bfloat16* a_base[4];
  const __hip_bfloat16* b_base[4];
  int lds_off[4];
#pragma unroll
  for (int it = 0; it < 4; ++it) {
    int flat = ((it * 4 + wave) << 6) + lane;
    int row = flat >> 3;
    int seg = flat & 7;
    int seg_g = seg ^ (row & 7);
    a_base[it] = ao + (((size_t)(m0 + row)) << 8) + seg_g * 8;
    b_base[it] = wob + (((size_t)(n0 + row)) << 8) + seg_g * 8;
    lds_off[it] = (it * 4 + wave) << 9;
  }

  f32x4 acc[4][4];
  const f32x4 zero = {0.f, 0.f, 0.f, 0.f};
#pragma unroll
  for (int i = 0; i < 4; ++i)
#pragma unroll
    for (int j = 0; j < 4; ++j) acc[i][j] = zero;

  for (int kt = 0; kt < 4; ++kt) {
    const int k0 = kt << 6;
#pragma unroll
    for (int it = 0; it < 4; ++it) {
      load_lds16(a_base[it] + k0, &As[lds_off[it]]);
      load_lds16(b_base[it] + k0, &Bs[lds_off[it]]);
    }
    __syncthreads();

#pragma unroll
    for (int kk = 0; kk < 64; kk += 32) {
      const int sx = (((kk >> 3) + quad) ^ (l16 & 7)) << 3;
      bf16x8 af[4], bfr[4];
#pragma unroll
      for (int i = 0; i < 4; ++i)
        af[i] = *(const bf16x8*)&As[((wm + i * 16 + l16) << 6) + sx];
#pragma unroll
      for (int j = 0; j < 4; ++j)
        bfr[j] = *(const bf16x8*)&Bs[((wn + j * 16 + l16) << 6) + sx];
#pragma unroll
      for (int i = 0; i < 4; ++i)
#pragma unroll
        for (int j = 0; j < 4; ++j)
          acc[i][j] = __builtin_amdgcn_mfma_f32_16x16x32_bf16(af[i], bfr[j],
                                                              acc[i][j], 0, 0, 0);
    }
    __syncthreads();
  }

#pragma unroll
  for (int i = 0; i < 4; ++i)
#pragma unroll
    for (int j = 0; j < 4; ++j) {
      int col = n0 + wn + j * 16 + l16;
      float bias = bo[col];
#pragma unroll
      for (int r = 0; r < 4; ++r) {
        int row = m0 + wm + i * 16 + quad * 4 + r;
        out[(size_t)row * 256 + col] = acc[i][j][r] + bias;
      }
    }
}

// ---------------------------------------------------------------------------
// launch
// ---------------------------------------------------------------------------
extern "C" void kernel_launch(void* const* d_in, const int* in_sizes, int n_in,
                              void* d_out, int out_size, void* d_ws, size_t ws_size,
                              hipStream_t stream) {
  const float* x     = (const float*)d_in[0];
  const float* wq    = (const float*)d_in[1];
  const float* wk    = (const float*)d_in[2];
  const float* wv    = (const float*)d_in[3];
  const float* gq    = (const float*)d_in[4];
  const float* bq    = (const float*)d_in[5];
  const float* gk    = (const float*)d_in[6];
  const float* bk    = (const float*)d_in[7];
  const float* gv    = (const float*)d_in[8];
  const float* bv    = (const float*)d_in[9];
  const float* rel   = (const float*)d_in[10];
  const float* gbias = (const float*)d_in[11];
  const float* alpha = (const float*)d_in[12];
  const float* wo    = (const float*)d_in[13];
  const float* bo    = (const float*)d_in[14];
  float* out = (float*)d_out;

  // workspace layout (bytes); total 420,741,632
  char* ws = (char*)d_ws;
  __hip_bfloat16* xb  = (__hip_bfloat16*)(ws);                 // 83,886,080
  __hip_bfloat16* y   = (__hip_bfloat16*)(ws + 83886080);      // 251,658,240
  __hip_bfloat16* ao  = (__hip_bfloat16*)(ws + 335544320);     // 83,886,080
  __hip_bfloat16* WcT = (__hip_bfloat16*)(ws + 419430400);     // 1,179,648
  __hip_bfloat16* wob = (__hip_bfloat16*)(ws + 420610048);     // 131,072
  int*            zr  = (int*)(ws + 420741120);                // 512

  prep_kernel<<<8192, 256, 0, stream>>>(x, wq, wk, wv, wo, xb, WcT, wob, zr);
  conv_gemm_kernel<<<dim3(1280, 6), 256, 0, stream>>>(xb, WcT, y,
                                                      (const __hip_bfloat16*)zr);
  ln_kernel<<<40960, 256, 0, stream>>>(y, xb, gq, bq, gk, bk, gv, bv);
  attn2_kernel<<<8192, 256, 0, stream>>>(y, rel, gbias, alpha, ao);
  proj_gemm_kernel<<<dim3(1280, 2), 256, 0, stream>>>(ao, wob, bo, out);
}